// Round 1
// baseline (892.024 us; speedup 1.0000x reference)
//
#include <hip/hip_runtime.h>

#define N_ROWS 32768
#define DDIM   512
#define KCODES 1024
#define DECAYF 0.99f
#define OMDF   0.01f
#define EPSF   1e-5f

// ---------------- K0: row sum-of-squares (cols = 512), one wave per row ----
__global__ void rowsumsq_kernel(const float* __restrict__ x,
                                float* __restrict__ out, int rows) {
    int wave = (int)((blockIdx.x * blockDim.x + threadIdx.x) >> 6);
    int lane = threadIdx.x & 63;
    if (wave >= rows) return;
    const float4* p = (const float4*)(x + (size_t)wave * DDIM);
    float4 a = p[lane];
    float4 b = p[lane + 64];
    float s = a.x*a.x + a.y*a.y + a.z*a.z + a.w*a.w
            + b.x*b.x + b.y*b.y + b.z*b.z + b.w*b.w;
    #pragma unroll
    for (int off = 32; off; off >>= 1) s += __shfl_down(s, off, 64);
    if (lane == 0) out[wave] = s;
}

// ---------------- K1: assign (distance GEMM + argmin) ----------------------
// Block: 256 threads, tile MT=64 rows x all K codes (chunks of NT=128).
#define MT 64
#define NT 128
#define DT 16
#define LDPA 68   // padded leading dim for A (64+4)
#define LDPB 132  // padded leading dim for B (128+4)

__global__ __launch_bounds__(256)
void assign_kernel(const float* __restrict__ ze, const float* __restrict__ cb,
                   const float* __restrict__ rownorm,
                   const float* __restrict__ colnorm,
                   int* __restrict__ idx_out, float* __restrict__ idx_f_out) {
    __shared__ float As[DT][LDPA];
    __shared__ float Bs[DT][LDPB];
    __shared__ float redv[MT][16];
    __shared__ int   redi[MT][16];

    const int tid = threadIdx.x;
    const int tx  = tid & 15;   // code direction (8 codes each)
    const int ty  = tid >> 4;   // row direction  (4 rows each, ty in 0..15)
    const int row0 = blockIdx.x * MT;

    // staging indices
    const int sr = tid >> 2;        // 0..63
    const int sc = (tid & 3) * 4;   // 0,4,8,12

    float bestv[4];
    int   besti[4];
    #pragma unroll
    for (int i = 0; i < 4; ++i) { bestv[i] = 3.4e38f; besti[i] = 0; }

    float rn[4];
    #pragma unroll
    for (int i = 0; i < 4; ++i) rn[i] = rownorm[row0 + ty*4 + i];

    for (int kc = 0; kc < KCODES; kc += NT) {
        float acc[4][8];
        #pragma unroll
        for (int i = 0; i < 4; ++i)
            #pragma unroll
            for (int j = 0; j < 8; ++j) acc[i][j] = 0.f;

        for (int d0 = 0; d0 < DDIM; d0 += DT) {
            __syncthreads();   // previous iter finished reading As/Bs
            // stage A: 64 rows x 16 d  (1 float4 per thread)
            {
                float4 a0 = *(const float4*)(ze + (size_t)(row0 + sr)*DDIM + d0 + sc);
                As[sc+0][sr] = a0.x; As[sc+1][sr] = a0.y;
                As[sc+2][sr] = a0.z; As[sc+3][sr] = a0.w;
            }
            // stage B: 128 codes x 16 d (2 float4 per thread)
            {
                float4 b0 = *(const float4*)(cb + (size_t)(kc + sr)*DDIM + d0 + sc);
                float4 b1 = *(const float4*)(cb + (size_t)(kc + sr + 64)*DDIM + d0 + sc);
                Bs[sc+0][sr]    = b0.x; Bs[sc+1][sr]    = b0.y;
                Bs[sc+2][sr]    = b0.z; Bs[sc+3][sr]    = b0.w;
                Bs[sc+0][sr+64] = b1.x; Bs[sc+1][sr+64] = b1.y;
                Bs[sc+2][sr+64] = b1.z; Bs[sc+3][sr+64] = b1.w;
            }
            __syncthreads();
            #pragma unroll
            for (int dd = 0; dd < DT; ++dd) {
                float a[4], b[8];
                *(float4*)&a[0] = *(const float4*)&As[dd][ty*4];
                *(float4*)&b[0] = *(const float4*)&Bs[dd][tx*8];
                *(float4*)&b[4] = *(const float4*)&Bs[dd][tx*8 + 4];
                #pragma unroll
                for (int i = 0; i < 4; ++i)
                    #pragma unroll
                    for (int j = 0; j < 8; ++j)
                        acc[i][j] = fmaf(a[i], b[j], acc[i][j]);
            }
        }
        // chunk epilogue: d2 = (||x||^2 - 2*dot) + ||c||^2, argmin update
        #pragma unroll
        for (int j = 0; j < 8; ++j) {
            int k = kc + tx*8 + j;
            float cn = colnorm[k];
            #pragma unroll
            for (int i = 0; i < 4; ++i) {
                float d2 = (rn[i] - 2.0f*acc[i][j]) + cn;
                if (d2 < bestv[i] || (d2 == bestv[i] && k < besti[i])) {
                    bestv[i] = d2; besti[i] = k;
                }
            }
        }
    }

    __syncthreads();
    #pragma unroll
    for (int i = 0; i < 4; ++i) {
        redv[ty*4 + i][tx] = bestv[i];
        redi[ty*4 + i][tx] = besti[i];
    }
    __syncthreads();
    if (tid < MT) {
        float bv = redv[tid][0]; int bi = redi[tid][0];
        #pragma unroll
        for (int t = 1; t < 16; ++t) {
            float v = redv[tid][t]; int i2 = redi[tid][t];
            if (v < bv || (v == bv && i2 < bi)) { bv = v; bi = i2; }
        }
        idx_out[row0 + tid]   = bi;
        idx_f_out[row0 + tid] = (float)bi;   // output 0 as float value
    }
}

// ---------------- K2: scatter counts + sums via atomics --------------------
__global__ void scatter_kernel(const float* __restrict__ ze,
                               const int* __restrict__ idx,
                               float* __restrict__ counts,
                               float* __restrict__ sums) {
    int wave = (int)((blockIdx.x * blockDim.x + threadIdx.x) >> 6);
    int lane = threadIdx.x & 63;
    if (wave >= N_ROWS) return;
    int k = idx[wave];
    if (lane == 0) atomicAdd(counts + k, 1.0f);
    const float4* zp = (const float4*)(ze + (size_t)wave * DDIM);
    float* sp = sums + (size_t)k * DDIM;
    float4 a = zp[lane];
    float4 b = zp[lane + 64];
    int d0 = lane * 4;
    atomicAdd(sp + d0 + 0, a.x); atomicAdd(sp + d0 + 1, a.y);
    atomicAdd(sp + d0 + 2, a.z); atomicAdd(sp + d0 + 3, a.w);
    atomicAdd(sp + 256 + d0 + 0, b.x); atomicAdd(sp + 256 + d0 + 1, b.y);
    atomicAdd(sp + 256 + d0 + 2, b.z); atomicAdd(sp + 256 + d0 + 3, b.w);
}

// ---------------- K3: finalize cluster sizes -> smoothed -------------------
__global__ void finalize_kernel(const float* __restrict__ ecs,
                                const float* __restrict__ counts,
                                float* __restrict__ smoothed) {
    __shared__ float red[1024];
    int t = threadIdx.x;
    float cs = DECAYF * ecs[t] + OMDF * counts[t];
    red[t] = cs;
    __syncthreads();
    for (int s = 512; s; s >>= 1) {
        if (t < s) red[t] += red[t + s];
        __syncthreads();
    }
    float n = red[0];
    smoothed[t] = (cs + EPSF) / (n + (float)KCODES * EPSF) * n;
}

// ---------------- K4: normalized codebook ----------------------------------
__global__ void cbn_kernel(const float* __restrict__ w,
                           const float* __restrict__ sums,
                           const float* __restrict__ smoothed,
                           float* __restrict__ cbn) {
    int i = blockIdx.x * blockDim.x + threadIdx.x;   // float4 index
    if (i >= KCODES * DDIM / 4) return;
    int k = i >> 7;                                   // D/4 = 128
    float4 ww = ((const float4*)w)[i];
    float4 ss = ((const float4*)sums)[i];
    float sm = smoothed[k];
    float4 o;
    o.x = (DECAYF*ww.x + OMDF*ss.x) / sm;
    o.y = (DECAYF*ww.y + OMDF*ss.y) / sm;
    o.z = (DECAYF*ww.z + OMDF*ss.z) / sm;
    o.w = (DECAYF*ww.w + OMDF*ss.w) / sm;
    ((float4*)cbn)[i] = o;
}

// ---------------- K5: gather quantized + straight-through ------------------
__global__ void gather_kernel(const float* __restrict__ ze,
                              const int* __restrict__ idx,
                              const float* __restrict__ cbn,
                              float* __restrict__ out_q,
                              float* __restrict__ out_st) {
    int wave = (int)((blockIdx.x * blockDim.x + threadIdx.x) >> 6);
    int lane = threadIdx.x & 63;
    if (wave >= N_ROWS) return;
    int k = idx[wave];
    const float4* qp = (const float4*)(cbn + (size_t)k * DDIM);
    const float4* zp = (const float4*)(ze + (size_t)wave * DDIM);
    float4* o1 = (float4*)(out_q  + (size_t)wave * DDIM);
    float4* o2 = (float4*)(out_st + (size_t)wave * DDIM);
    #pragma unroll
    for (int i = 0; i < 2; ++i) {
        float4 q = qp[lane + 64*i];
        float4 z = zp[lane + 64*i];
        float4 st;
        st.x = z.x + (q.x - z.x);
        st.y = z.y + (q.y - z.y);
        st.z = z.z + (q.z - z.z);
        st.w = z.w + (q.w - z.w);
        o1[lane + 64*i] = q;
        o2[lane + 64*i] = st;
    }
}

// ---------------- launch ----------------------------------------------------
extern "C" void kernel_launch(void* const* d_in, const int* in_sizes, int n_in,
                              void* d_out, int out_size, void* d_ws, size_t ws_size,
                              hipStream_t stream) {
    const float* ze  = (const float*)d_in[0];   // [32768, 512]
    const float* cb  = (const float*)d_in[1];   // [1024, 512]
    const float* ecs = (const float*)d_in[2];   // [1024]
    const float* ew  = (const float*)d_in[3];   // [1024, 512]

    float* out = (float*)d_out;
    float* out_idx = out;                       // 32768
    float* out_q   = out + 32768;               // 16777216
    float* out_st  = out + 32768 + 16777216;    // 16777216

    char* ws = (char*)d_ws;
    int*   idx_i    = (int*)  (ws + 0);         // 128 KB
    float* rownorm  = (float*)(ws + 131072);    // 128 KB
    float* colnorm  = (float*)(ws + 262144);    // 4 KB
    float* smoothed = (float*)(ws + 266240);    // 4 KB
    float* counts   = (float*)(ws + 270336);    // 4 KB
    float* sums     = (float*)(ws + 274432);    // 2 MB
    float* cbn      = (float*)(ws + 2371584);   // 2 MB

    // zero counts + sums (contiguous region)
    hipMemsetAsync(ws + 270336, 0, 4096 + 2097152, stream);

    rowsumsq_kernel<<<N_ROWS/4, 256, 0, stream>>>(ze, rownorm, N_ROWS);
    rowsumsq_kernel<<<KCODES/4, 256, 0, stream>>>(cb, colnorm, KCODES);

    assign_kernel<<<N_ROWS/MT, 256, 0, stream>>>(ze, cb, rownorm, colnorm,
                                                 idx_i, out_idx);

    scatter_kernel<<<N_ROWS/4, 256, 0, stream>>>(ze, idx_i, counts, sums);

    finalize_kernel<<<1, 1024, 0, stream>>>(ecs, counts, smoothed);

    cbn_kernel<<<(KCODES*DDIM/4 + 255)/256, 256, 0, stream>>>(ew, sums, smoothed, cbn);

    gather_kernel<<<N_ROWS/4, 256, 0, stream>>>(ze, idx_i, cbn, out_q, out_st);
}